// Round 16
// baseline (121.877 us; speedup 1.0000x reference)
//
#include <hip/hip_runtime.h>
#include <cstdint>
#include <cstddef>

#define N_ROWS 16384   // B*T
#define KCODES 4096
#define DIM    256
#define CAP    128     // geometric tail, mean ~7.8: P(row overflow) ~ 1e-7

// -------- kernel 1: codebook inverse norms --------
__global__ __launch_bounds__(256) void cinv_kernel(
    const float* __restrict__ cb, float* __restrict__ cinv)
{
    int r    = blockIdx.x * 4 + (threadIdx.x >> 6);   // one wave per codebook row
    int lane = threadIdx.x & 63;
    float4 v = reinterpret_cast<const float4*>(cb + (size_t)r * DIM)[lane];
    float s = v.x*v.x + v.y*v.y + v.z*v.z + v.w*v.w;
    #pragma unroll
    for (int m = 1; m <= 32; m <<= 1) s += __shfl_xor(s, m);
    if (lane == 0) cinv[r] = 1.0f / fmaxf(sqrtf(s), 1e-12f);
}

// -------- kernel 2: pure-stream scan (R14 phase 1 + global candidate store) --------
// Block per row. Minimal tail: block umax -> u-space threshold -> register
// re-filter -> ~8 global candidate stores. No eval, no z, no output writes:
// streaming duty-cycle stays high.
__global__ __launch_bounds__(256) void scan_kernel(
    const float* __restrict__ u, int* __restrict__ gcnt,
    float2* __restrict__ gcand)
{
    const int row  = blockIdx.x;
    const int t    = threadIdx.x, lane = t & 63, wave = t >> 6;

    __shared__ float s_max[4];

    const float4* ur4 = reinterpret_cast<const float4*>(u + (size_t)row * KCODES);
    float4 v[4];
    #pragma unroll
    for (int k = 0; k < 4; ++k) v[k] = ur4[k * 256 + t];

    float um = -1.0f;
    #pragma unroll
    for (int k = 0; k < 4; ++k)
        um = fmaxf(um, fmaxf(fmaxf(v[k].x, v[k].y), fmaxf(v[k].z, v[k].w)));
    #pragma unroll
    for (int m = 1; m <= 32; m <<= 1) um = fmaxf(um, __shfl_xor(um, m));
    if (lane == 0) s_max[wave] = um;
    __syncthreads();
    const float umax = fmaxf(fmaxf(s_max[0], s_max[1]), fmaxf(s_max[2], s_max[3]));

    // invert: g(u) = -log(-log(u+1e-10)+1e-10) monotone in u.
    // winner needs g >= gmax - 2 (cos-spread <= 2); margin 2.06 + ulp shrink.
    const float gmax  = -logf(-logf(umax + 1e-10f) + 1e-10f);
    const float y_thr = expf(-(gmax - 2.06f)) - 1e-10f;
    float u_thr = expf(-y_thr) - 1e-10f;
    u_thr = u_thr - fabsf(u_thr) * 2e-6f - 1e-12f;   // few-ulp safety shrink

    #pragma unroll
    for (int k = 0; k < 4; ++k) {
        float vv[4] = {v[k].x, v[k].y, v[k].z, v[k].w};
        #pragma unroll
        for (int e = 0; e < 4; ++e) {
            if (vv[e] >= u_thr) {
                int pos = atomicAdd(&gcnt[row], 1);
                if (pos < CAP)
                    gcand[(size_t)row * CAP + pos] =
                        make_float2(vv[e], (float)((k * 256 + t) * 4 + e));
            }
        }
    }
}

// -------- kernel 3: exact select + gather (R14 phases 2+3, candidates from ws) --------
__global__ __launch_bounds__(256) void select_kernel(
    const float* __restrict__ u, const float* __restrict__ z,
    const float* __restrict__ cb, const float* __restrict__ cinv,
    const int* __restrict__ gcnt, const float2* __restrict__ gcand,
    float* __restrict__ zq, float* __restrict__ emb,
    float* __restrict__ idx_out, float* __restrict__ commit_part)
{
    const int row  = blockIdx.x;
    const int t    = threadIdx.x, lane = t & 63, wave = t >> 6;

    __shared__ float s_bestv[4];
    __shared__ int   s_besti[4];

    const int n = gcnt[row];

    // threshold only needed for the (effectively never) fallback
    float4 zv = reinterpret_cast<const float4*>(z + (size_t)row * DIM)[lane];
    float ss = zv.x*zv.x + zv.y*zv.y + zv.z*zv.z + zv.w*zv.w;
    #pragma unroll
    for (int m = 1; m <= 32; m <<= 1) ss += __shfl_xor(ss, m);
    const float zinv = 1.0f / fmaxf(sqrtf(ss), 1e-12f);
    float4 zn;
    zn.x = zv.x*zinv; zn.y = zv.y*zinv; zn.z = zv.z*zinv; zn.w = zv.w*zinv;

    float best = -3.0e38f;
    int   bi   = 1 << 30;

    auto evalc = [&](float uu, int col) {
        float4 cv = reinterpret_cast<const float4*>(cb + (size_t)col * DIM)[lane];
        float civ = cinv[col];
        float d = zn.x*(cv.x*civ) + zn.y*(cv.y*civ) + zn.z*(cv.z*civ) + zn.w*(cv.w*civ);
        #pragma unroll
        for (int m = 1; m <= 32; m <<= 1) d += __shfl_xor(d, m);
        float y1 = -logf(uu + 1e-10f);
        float g  = -logf(y1 + 1e-10f);
        float val = (d - 1.0f) + g;
        if (val > best || (val == best && col < bi)) { best = val; bi = col; }
    };

    if (n <= CAP) {
        for (int c = wave; c < n; c += 4) {
            float2 cd = gcand[(size_t)row * CAP + c];
            evalc(cd.x, (int)cd.y);
        }
    } else {
        // exact full-row fallback: recompute threshold, re-read u (rare)
        const float4* ur4 = reinterpret_cast<const float4*>(u + (size_t)row * KCODES);
        float um = -1.0f;
        for (int k = 0; k < 4; ++k) {
            float4 vv = ur4[k * 256 + t];
            um = fmaxf(um, fmaxf(fmaxf(vv.x, vv.y), fmaxf(vv.z, vv.w)));
        }
        #pragma unroll
        for (int m = 1; m <= 32; m <<= 1) um = fmaxf(um, __shfl_xor(um, m));
        __shared__ float s_fmax[4];
        if (lane == 0) s_fmax[wave] = um;
        __syncthreads();
        const float umax = fmaxf(fmaxf(s_fmax[0], s_fmax[1]), fmaxf(s_fmax[2], s_fmax[3]));
        const float gmax  = -logf(-logf(umax + 1e-10f) + 1e-10f);
        const float y_thr = expf(-(gmax - 2.06f)) - 1e-10f;
        float u_thr = expf(-y_thr) - 1e-10f;
        u_thr = u_thr - fabsf(u_thr) * 2e-6f - 1e-12f;
        const float* urow = u + (size_t)row * KCODES;
        for (int col = wave; col < KCODES; col += 4) {
            float uu = urow[col];
            if (uu >= u_thr) evalc(uu, col);
        }
    }
    if (lane == 0) { s_bestv[wave] = best; s_besti[wave] = bi; }
    __syncthreads();

    best = s_bestv[0]; bi = s_besti[0];
    #pragma unroll
    for (int w = 1; w < 4; ++w) {
        float ov = s_bestv[w]; int oi = s_besti[w];
        if (ov > best || (ov == best && oi < bi)) { best = ov; bi = oi; }
    }
    if (wave == 0) {
        float4 cw = reinterpret_cast<const float4*>(cb + (size_t)bi * DIM)[lane];
        reinterpret_cast<float4*>(zq + (size_t)row * DIM)[lane] = cw;
        float dx = cw.x - zv.x, dy = cw.y - zv.y, dz = cw.z - zv.z, dw = cw.w - zv.w;
        float s2 = dx*dx + dy*dy + dz*dz + dw*dw;
        #pragma unroll
        for (int m = 1; m <= 32; m <<= 1) s2 += __shfl_xor(s2, m);
        if (lane == 0) {
            idx_out[row]     = (float)bi;
            commit_part[row] = s2;
        }
    } else if (wave == 1) {
        float4 cw = reinterpret_cast<const float4*>(cb + (size_t)bi * DIM)[lane];
        reinterpret_cast<float4*>(emb + (size_t)row * DIM)[lane] = cw;
    }
}

// -------- kernel 4: parallel commit reduction (16 blocks, float4 loads) --------
__global__ __launch_bounds__(256) void commit_reduce_kernel(
    const float* __restrict__ commit_part, float* __restrict__ commit_acc)
{
    __shared__ float red[256];
    const int t = threadIdx.x;
    float4 v = reinterpret_cast<const float4*>(commit_part)[blockIdx.x * 256 + t];
    red[t] = v.x + v.y + v.z + v.w;
    __syncthreads();
    for (int w = 128; w > 0; w >>= 1) { if (t < w) red[t] += red[t + w]; __syncthreads(); }
    if (t == 0) atomicAdd(commit_acc, red[0]);
}

// -------- kernel 5: scalars (commitment, entropy bonus, perplexity, entropy) --------
__global__ __launch_bounds__(256) void scalars_kernel(
    const float* __restrict__ commit_acc, const float* __restrict__ usage,
    const int* __restrict__ step_ptr, float* __restrict__ out4)
{
    __shared__ float red[256];
    int t = threadIdx.x;

    float us = 0.f;
    for (int i = t; i < KCODES; i += 256) us += usage[i];
    red[t] = us; __syncthreads();
    for (int w = 128; w > 0; w >>= 1) { if (t < w) red[t] += red[t + w]; __syncthreads(); }
    float usage_sum = red[0];
    __syncthreads();

    float e = 0.f;
    for (int i = t; i < KCODES; i += 256) {
        float p = (usage_sum > 0.f) ? usage[i] / (usage_sum + 1e-10f) : (1.0f / KCODES);
        e += p * logf(p + 1e-10f);
    }
    red[t] = e; __syncthreads();
    for (int w = 128; w > 0; w >>= 1) { if (t < w) red[t] += red[t + w]; __syncthreads(); }

    if (t == 0) {
        float entropy = -red[0];
        int step_after = step_ptr[0] + 1;
        float bonus_w = 0.05f * (1.0f - (float)step_after / 20000.0f);
        float eb = (step_after < 20000) ? (-bonus_w * entropy) : 0.0f;
        out4[0] = 0.5f * commit_acc[0] / 4194304.0f;
        out4[1] = eb;
        out4[2] = expf(entropy);
        out4[3] = entropy;
    }
}

extern "C" void kernel_launch(void* const* d_in, const int* in_sizes, int n_in,
                              void* d_out, int out_size, void* d_ws, size_t ws_size,
                              hipStream_t stream)
{
    const float* z     = (const float*)d_in[0];   // [16,1024,256]
    const float* u     = (const float*)d_in[1];   // [16,1024,4096]
    const float* cb    = (const float*)d_in[2];   // [4096,256]
    const float* usage = (const float*)d_in[3];   // [4096]
    const int*   step  = (const int*)d_in[4];     // scalar

    float* out  = (float*)d_out;
    float* zq   = out;                 // 4194304
    float* emb  = out + 4194304;       // 4194304
    float* idxo = out + 8388608;       // 16384
    float* scal = out + 8404992;       // 4

    float*  ws          = (float*)d_ws;
    float*  cinv        = ws;                       // 4096
    float*  commit_part = ws + 4096;                // 16384
    float*  commit_acc  = ws + 20480;               // 1 (+pad)
    int*    gcnt        = (int*)(ws + 20608);       // 16384
    float2* gcand       = (float2*)(ws + 36992);    // 16384*CAP float2 (16 MB)

    hipMemsetAsync(commit_acc, 0, sizeof(float), stream);
    hipMemsetAsync(gcnt, 0, N_ROWS * sizeof(int), stream);
    hipLaunchKernelGGL(cinv_kernel, dim3(1024), dim3(256), 0, stream, cb, cinv);
    hipLaunchKernelGGL(scan_kernel, dim3(N_ROWS), dim3(256), 0, stream,
                       u, gcnt, gcand);
    hipLaunchKernelGGL(select_kernel, dim3(N_ROWS), dim3(256), 0, stream,
                       u, z, cb, cinv, gcnt, gcand, zq, emb, idxo, commit_part);
    hipLaunchKernelGGL(commit_reduce_kernel, dim3(16), dim3(256), 0, stream,
                       commit_part, commit_acc);
    hipLaunchKernelGGL(scalars_kernel, dim3(1), dim3(256), 0, stream,
                       commit_acc, usage, step, scal);
}

// Round 17
// 90.008 us; speedup vs baseline: 1.3541x; 1.3541x over previous
//
#include <hip/hip_runtime.h>
#include <cstdint>
#include <cstddef>

#define N_ROWS 16384   // B*T
#define KCODES 4096
#define DIM    256
#define CAP    128     // geometric tail, mean ~7.8: P(row overflow) ~ 1e-7

// -------- kernel 1: codebook inverse norms --------
__global__ __launch_bounds__(256) void cinv_kernel(
    const float* __restrict__ cb, float* __restrict__ cinv)
{
    int r    = blockIdx.x * 4 + (threadIdx.x >> 6);   // one wave per codebook row
    int lane = threadIdx.x & 63;
    float4 v = reinterpret_cast<const float4*>(cb + (size_t)r * DIM)[lane];
    float s = v.x*v.x + v.y*v.y + v.z*v.z + v.w*v.w;
    #pragma unroll
    for (int m = 1; m <= 32; m <<= 1) s += __shfl_xor(s, m);
    if (lane == 0) cinv[r] = 1.0f / fmaxf(sqrtf(s), 1e-12f);
}

// -------- kernel 2: fused per-row scan + exact select + gather --------
// R14-verified body; single delta: zv load hoisted above the first barrier
// so its latency drains under the u-max sync instead of serializing phase 2.
__global__ __launch_bounds__(256) void row_kernel(
    const float* __restrict__ u, const float* __restrict__ z,
    const float* __restrict__ cb, const float* __restrict__ cinv,
    float* __restrict__ zq, float* __restrict__ emb,
    float* __restrict__ idx_out, float* __restrict__ commit_part)
{
    const int row  = blockIdx.x;
    const int t    = threadIdx.x, lane = t & 63, wave = t >> 6;

    __shared__ float2 cand[CAP];
    __shared__ int    s_cnt;
    __shared__ float  s_max[4];
    __shared__ float  s_bestv[4];
    __shared__ int    s_besti[4];

    if (t == 0) s_cnt = 0;

    // ---- phase 1: stream u row, block umax, u-space threshold, collect ----
    const float4* ur4 = reinterpret_cast<const float4*>(u + (size_t)row * KCODES);
    float4 v[4];
    #pragma unroll
    for (int k = 0; k < 4; ++k) v[k] = ur4[k * 256 + t];

    float4 zv = reinterpret_cast<const float4*>(z + (size_t)row * DIM)[lane];  // prefetch

    float um = -1.0f;
    #pragma unroll
    for (int k = 0; k < 4; ++k)
        um = fmaxf(um, fmaxf(fmaxf(v[k].x, v[k].y), fmaxf(v[k].z, v[k].w)));
    #pragma unroll
    for (int m = 1; m <= 32; m <<= 1) um = fmaxf(um, __shfl_xor(um, m));
    if (lane == 0) s_max[wave] = um;
    __syncthreads();
    const float umax = fmaxf(fmaxf(s_max[0], s_max[1]), fmaxf(s_max[2], s_max[3]));

    // invert: g(u) = -log(-log(u+1e-10)+1e-10) monotone in u.
    // winner needs g >= gmax - 2 (cos-spread <= 2); margin 2.06 + ulp shrink.
    const float gmax  = -logf(-logf(umax + 1e-10f) + 1e-10f);
    const float y_thr = expf(-(gmax - 2.06f)) - 1e-10f;
    float u_thr = expf(-y_thr) - 1e-10f;
    u_thr = u_thr - fabsf(u_thr) * 2e-6f - 1e-12f;   // few-ulp safety shrink

    #pragma unroll
    for (int k = 0; k < 4; ++k) {
        float vv[4] = {v[k].x, v[k].y, v[k].z, v[k].w};
        #pragma unroll
        for (int e = 0; e < 4; ++e) {
            if (vv[e] >= u_thr) {
                int pos = atomicAdd(&s_cnt, 1);
                if (pos < CAP)
                    cand[pos] = make_float2(vv[e], (float)((k * 256 + t) * 4 + e));
            }
        }
    }
    __syncthreads();
    const int n = s_cnt;

    // ---- phase 2: z normalize (per wave), candidate eval split across waves ----
    float ss = zv.x*zv.x + zv.y*zv.y + zv.z*zv.z + zv.w*zv.w;
    #pragma unroll
    for (int m = 1; m <= 32; m <<= 1) ss += __shfl_xor(ss, m);
    const float zinv = 1.0f / fmaxf(sqrtf(ss), 1e-12f);
    float4 zn;
    zn.x = zv.x*zinv; zn.y = zv.y*zinv; zn.z = zv.z*zinv; zn.w = zv.w*zinv;

    float best = -3.0e38f;
    int   bi   = 1 << 30;

    auto evalc = [&](float uu, int col) {
        float4 cv = reinterpret_cast<const float4*>(cb + (size_t)col * DIM)[lane];
        float civ = cinv[col];
        float d = zn.x*(cv.x*civ) + zn.y*(cv.y*civ) + zn.z*(cv.z*civ) + zn.w*(cv.w*civ);
        #pragma unroll
        for (int m = 1; m <= 32; m <<= 1) d += __shfl_xor(d, m);
        float y1 = -logf(uu + 1e-10f);
        float g  = -logf(y1 + 1e-10f);
        float val = (d - 1.0f) + g;
        if (val > best || (val == best && col < bi)) { best = val; bi = col; }
    };

    if (n <= CAP) {
        for (int c = wave; c < n; c += 4) {
            float2 cd = cand[c];
            evalc(cd.x, (int)cd.y);
        }
    } else {
        // exact full-row fallback, wave-parallel (effectively never taken)
        const float* urow = u + (size_t)row * KCODES;
        for (int col = wave; col < KCODES; col += 4) {
            float uu = urow[col];
            if (uu >= u_thr) evalc(uu, col);
        }
    }
    if (lane == 0) { s_bestv[wave] = best; s_besti[wave] = bi; }
    __syncthreads();

    // ---- phase 3: all waves combine; wave0 -> zq+commit, wave1 -> emb ----
    best = s_bestv[0]; bi = s_besti[0];
    #pragma unroll
    for (int w = 1; w < 4; ++w) {
        float ov = s_bestv[w]; int oi = s_besti[w];
        if (ov > best || (ov == best && oi < bi)) { best = ov; bi = oi; }
    }
    if (wave == 0) {
        float4 cw = reinterpret_cast<const float4*>(cb + (size_t)bi * DIM)[lane];
        reinterpret_cast<float4*>(zq + (size_t)row * DIM)[lane] = cw;
        float dx = cw.x - zv.x, dy = cw.y - zv.y, dz = cw.z - zv.z, dw = cw.w - zv.w;
        float s2 = dx*dx + dy*dy + dz*dz + dw*dw;
        #pragma unroll
        for (int m = 1; m <= 32; m <<= 1) s2 += __shfl_xor(s2, m);
        if (lane == 0) {
            idx_out[row]     = (float)bi;
            commit_part[row] = s2;
        }
    } else if (wave == 1) {
        float4 cw = reinterpret_cast<const float4*>(cb + (size_t)bi * DIM)[lane];
        reinterpret_cast<float4*>(emb + (size_t)row * DIM)[lane] = cw;
    }
}

// -------- kernel 3: parallel commit reduction (16 blocks -> 16 partials) --------
__global__ __launch_bounds__(256) void commit_reduce_kernel(
    const float* __restrict__ commit_part, float* __restrict__ commit_blk)
{
    __shared__ float red[256];
    const int t = threadIdx.x;
    float4 v = reinterpret_cast<const float4*>(commit_part)[blockIdx.x * 256 + t];
    red[t] = v.x + v.y + v.z + v.w;
    __syncthreads();
    for (int w = 128; w > 0; w >>= 1) { if (t < w) red[t] += red[t + w]; __syncthreads(); }
    if (t == 0) commit_blk[blockIdx.x] = red[0];
}

// -------- kernel 4: scalars (commitment, entropy bonus, perplexity, entropy) --------
__global__ __launch_bounds__(256) void scalars_kernel(
    const float* __restrict__ commit_blk, const float* __restrict__ usage,
    const int* __restrict__ step_ptr, float* __restrict__ out4)
{
    __shared__ float red[256];
    int t = threadIdx.x;

    float us = 0.f;
    for (int i = t; i < KCODES; i += 256) us += usage[i];
    red[t] = us; __syncthreads();
    for (int w = 128; w > 0; w >>= 1) { if (t < w) red[t] += red[t + w]; __syncthreads(); }
    float usage_sum = red[0];
    __syncthreads();

    float e = 0.f;
    for (int i = t; i < KCODES; i += 256) {
        float p = (usage_sum > 0.f) ? usage[i] / (usage_sum + 1e-10f) : (1.0f / KCODES);
        e += p * logf(p + 1e-10f);
    }
    red[t] = e; __syncthreads();
    for (int w = 128; w > 0; w >>= 1) { if (t < w) red[t] += red[t + w]; __syncthreads(); }

    if (t == 0) {
        float csum = 0.f;
        #pragma unroll
        for (int i = 0; i < 16; ++i) csum += commit_blk[i];
        float entropy = -red[0];
        int step_after = step_ptr[0] + 1;
        float bonus_w = 0.05f * (1.0f - (float)step_after / 20000.0f);
        float eb = (step_after < 20000) ? (-bonus_w * entropy) : 0.0f;
        out4[0] = 0.5f * csum / 4194304.0f;
        out4[1] = eb;
        out4[2] = expf(entropy);
        out4[3] = entropy;
    }
}

extern "C" void kernel_launch(void* const* d_in, const int* in_sizes, int n_in,
                              void* d_out, int out_size, void* d_ws, size_t ws_size,
                              hipStream_t stream)
{
    const float* z     = (const float*)d_in[0];   // [16,1024,256]
    const float* u     = (const float*)d_in[1];   // [16,1024,4096]
    const float* cb    = (const float*)d_in[2];   // [4096,256]
    const float* usage = (const float*)d_in[3];   // [4096]
    const int*   step  = (const int*)d_in[4];     // scalar

    float* out  = (float*)d_out;
    float* zq   = out;                 // 4194304
    float* emb  = out + 4194304;       // 4194304
    float* idxo = out + 8388608;       // 16384
    float* scal = out + 8404992;       // 4

    float* ws          = (float*)d_ws;
    float* cinv        = ws;           // 4096
    float* commit_part = ws + 4096;    // 16384
    float* commit_blk  = ws + 20480;   // 16

    hipLaunchKernelGGL(cinv_kernel, dim3(1024), dim3(256), 0, stream, cb, cinv);
    hipLaunchKernelGGL(row_kernel, dim3(N_ROWS), dim3(256), 0, stream,
                       u, z, cb, cinv, zq, emb, idxo, commit_part);
    hipLaunchKernelGGL(commit_reduce_kernel, dim3(16), dim3(256), 0, stream,
                       commit_part, commit_blk);
    hipLaunchKernelGGL(scalars_kernel, dim3(1), dim3(256), 0, stream,
                       commit_blk, usage, step, scal);
}

// Round 19
// 84.264 us; speedup vs baseline: 1.4464x; 1.0682x over previous
//
#include <hip/hip_runtime.h>
#include <cstdint>
#include <cstddef>

#define N_ROWS 16384   // B*T
#define KCODES 4096
#define DIM    256
#define CAP    128     // geometric tail, mean ~7.8: P(row overflow) ~ 1e-7

typedef float fvec4 __attribute__((ext_vector_type(4)));   // nt-load compatible

// -------- kernel 1: codebook inverse norms --------
__global__ __launch_bounds__(256) void cinv_kernel(
    const float* __restrict__ cb, float* __restrict__ cinv)
{
    int r    = blockIdx.x * 4 + (threadIdx.x >> 6);   // one wave per codebook row
    int lane = threadIdx.x & 63;
    float4 v = reinterpret_cast<const float4*>(cb + (size_t)r * DIM)[lane];
    float s = v.x*v.x + v.y*v.y + v.z*v.z + v.w*v.w;
    #pragma unroll
    for (int m = 1; m <= 32; m <<= 1) s += __shfl_xor(s, m);
    if (lane == 0) cinv[r] = 1.0f / fmaxf(sqrtf(s), 1e-12f);
}

// -------- kernel 2: fused per-row scan + exact select + gather --------
// R17-verified body; single delta: u loads are NON-TEMPORAL via ext_vector
// (u is 268 MB read-once; nt keeps the 4 MB codebook resident in L2 for the
// eval tail).
__global__ __launch_bounds__(256) void row_kernel(
    const float* __restrict__ u, const float* __restrict__ z,
    const float* __restrict__ cb, const float* __restrict__ cinv,
    float* __restrict__ zq, float* __restrict__ emb,
    float* __restrict__ idx_out, float* __restrict__ commit_part)
{
    const int row  = blockIdx.x;
    const int t    = threadIdx.x, lane = t & 63, wave = t >> 6;

    __shared__ float2 cand[CAP];
    __shared__ int    s_cnt;
    __shared__ float  s_max[4];
    __shared__ float  s_bestv[4];
    __shared__ int    s_besti[4];

    if (t == 0) s_cnt = 0;

    // ---- phase 1: stream u row (nt), block umax, u-space threshold, collect ----
    const fvec4* ur4 = reinterpret_cast<const fvec4*>(u + (size_t)row * KCODES);
    fvec4 v[4];
    #pragma unroll
    for (int k = 0; k < 4; ++k) v[k] = __builtin_nontemporal_load(&ur4[k * 256 + t]);

    float4 zv = reinterpret_cast<const float4*>(z + (size_t)row * DIM)[lane];  // prefetch

    float um = -1.0f;
    #pragma unroll
    for (int k = 0; k < 4; ++k)
        um = fmaxf(um, fmaxf(fmaxf(v[k].x, v[k].y), fmaxf(v[k].z, v[k].w)));
    #pragma unroll
    for (int m = 1; m <= 32; m <<= 1) um = fmaxf(um, __shfl_xor(um, m));
    if (lane == 0) s_max[wave] = um;
    __syncthreads();
    const float umax = fmaxf(fmaxf(s_max[0], s_max[1]), fmaxf(s_max[2], s_max[3]));

    // invert: g(u) = -log(-log(u+1e-10)+1e-10) monotone in u.
    // winner needs g >= gmax - 2 (cos-spread <= 2); margin 2.06 + ulp shrink.
    const float gmax  = -logf(-logf(umax + 1e-10f) + 1e-10f);
    const float y_thr = expf(-(gmax - 2.06f)) - 1e-10f;
    float u_thr = expf(-y_thr) - 1e-10f;
    u_thr = u_thr - fabsf(u_thr) * 2e-6f - 1e-12f;   // few-ulp safety shrink

    #pragma unroll
    for (int k = 0; k < 4; ++k) {
        float vv[4] = {v[k].x, v[k].y, v[k].z, v[k].w};
        #pragma unroll
        for (int e = 0; e < 4; ++e) {
            if (vv[e] >= u_thr) {
                int pos = atomicAdd(&s_cnt, 1);
                if (pos < CAP)
                    cand[pos] = make_float2(vv[e], (float)((k * 256 + t) * 4 + e));
            }
        }
    }
    __syncthreads();
    const int n = s_cnt;

    // ---- phase 2: z normalize (per wave), candidate eval split across waves ----
    float ss = zv.x*zv.x + zv.y*zv.y + zv.z*zv.z + zv.w*zv.w;
    #pragma unroll
    for (int m = 1; m <= 32; m <<= 1) ss += __shfl_xor(ss, m);
    const float zinv = 1.0f / fmaxf(sqrtf(ss), 1e-12f);
    float4 zn;
    zn.x = zv.x*zinv; zn.y = zv.y*zinv; zn.z = zv.z*zinv; zn.w = zv.w*zinv;

    float best = -3.0e38f;
    int   bi   = 1 << 30;

    auto evalc = [&](float uu, int col) {
        float4 cv = reinterpret_cast<const float4*>(cb + (size_t)col * DIM)[lane];
        float civ = cinv[col];
        float d = zn.x*(cv.x*civ) + zn.y*(cv.y*civ) + zn.z*(cv.z*civ) + zn.w*(cv.w*civ);
        #pragma unroll
        for (int m = 1; m <= 32; m <<= 1) d += __shfl_xor(d, m);
        float y1 = -logf(uu + 1e-10f);
        float g  = -logf(y1 + 1e-10f);
        float val = (d - 1.0f) + g;
        if (val > best || (val == best && col < bi)) { best = val; bi = col; }
    };

    if (n <= CAP) {
        for (int c = wave; c < n; c += 4) {
            float2 cd = cand[c];
            evalc(cd.x, (int)cd.y);
        }
    } else {
        // exact full-row fallback, wave-parallel (effectively never taken)
        const float* urow = u + (size_t)row * KCODES;
        for (int col = wave; col < KCODES; col += 4) {
            float uu = __builtin_nontemporal_load(&urow[col]);
            if (uu >= u_thr) evalc(uu, col);
        }
    }
    if (lane == 0) { s_bestv[wave] = best; s_besti[wave] = bi; }
    __syncthreads();

    // ---- phase 3: all waves combine; wave0 -> zq+commit, wave1 -> emb ----
    best = s_bestv[0]; bi = s_besti[0];
    #pragma unroll
    for (int w = 1; w < 4; ++w) {
        float ov = s_bestv[w]; int oi = s_besti[w];
        if (ov > best || (ov == best && oi < bi)) { best = ov; bi = oi; }
    }
    if (wave == 0) {
        float4 cw = reinterpret_cast<const float4*>(cb + (size_t)bi * DIM)[lane];
        reinterpret_cast<float4*>(zq + (size_t)row * DIM)[lane] = cw;
        float dx = cw.x - zv.x, dy = cw.y - zv.y, dz = cw.z - zv.z, dw = cw.w - zv.w;
        float s2 = dx*dx + dy*dy + dz*dz + dw*dw;
        #pragma unroll
        for (int m = 1; m <= 32; m <<= 1) s2 += __shfl_xor(s2, m);
        if (lane == 0) {
            idx_out[row]     = (float)bi;
            commit_part[row] = s2;
        }
    } else if (wave == 1) {
        float4 cw = reinterpret_cast<const float4*>(cb + (size_t)bi * DIM)[lane];
        reinterpret_cast<float4*>(emb + (size_t)row * DIM)[lane] = cw;
    }
}

// -------- kernel 3: parallel commit reduction (16 blocks -> 16 partials) --------
__global__ __launch_bounds__(256) void commit_reduce_kernel(
    const float* __restrict__ commit_part, float* __restrict__ commit_blk)
{
    __shared__ float red[256];
    const int t = threadIdx.x;
    float4 v = reinterpret_cast<const float4*>(commit_part)[blockIdx.x * 256 + t];
    red[t] = v.x + v.y + v.z + v.w;
    __syncthreads();
    for (int w = 128; w > 0; w >>= 1) { if (t < w) red[t] += red[t + w]; __syncthreads(); }
    if (t == 0) commit_blk[blockIdx.x] = red[0];
}

// -------- kernel 4: scalars (commitment, entropy bonus, perplexity, entropy) --------
__global__ __launch_bounds__(256) void scalars_kernel(
    const float* __restrict__ commit_blk, const float* __restrict__ usage,
    const int* __restrict__ step_ptr, float* __restrict__ out4)
{
    __shared__ float red[256];
    int t = threadIdx.x;

    float us = 0.f;
    for (int i = t; i < KCODES; i += 256) us += usage[i];
    red[t] = us; __syncthreads();
    for (int w = 128; w > 0; w >>= 1) { if (t < w) red[t] += red[t + w]; __syncthreads(); }
    float usage_sum = red[0];
    __syncthreads();

    float e = 0.f;
    for (int i = t; i < KCODES; i += 256) {
        float p = (usage_sum > 0.f) ? usage[i] / (usage_sum + 1e-10f) : (1.0f / KCODES);
        e += p * logf(p + 1e-10f);
    }
    red[t] = e; __syncthreads();
    for (int w = 128; w > 0; w >>= 1) { if (t < w) red[t] += red[t + w]; __syncthreads(); }

    if (t == 0) {
        float csum = 0.f;
        #pragma unroll
        for (int i = 0; i < 16; ++i) csum += commit_blk[i];
        float entropy = -red[0];
        int step_after = step_ptr[0] + 1;
        float bonus_w = 0.05f * (1.0f - (float)step_after / 20000.0f);
        float eb = (step_after < 20000) ? (-bonus_w * entropy) : 0.0f;
        out4[0] = 0.5f * csum / 4194304.0f;
        out4[1] = eb;
        out4[2] = expf(entropy);
        out4[3] = entropy;
    }
}

extern "C" void kernel_launch(void* const* d_in, const int* in_sizes, int n_in,
                              void* d_out, int out_size, void* d_ws, size_t ws_size,
                              hipStream_t stream)
{
    const float* z     = (const float*)d_in[0];   // [16,1024,256]
    const float* u     = (const float*)d_in[1];   // [16,1024,4096]
    const float* cb    = (const float*)d_in[2];   // [4096,256]
    const float* usage = (const float*)d_in[3];   // [4096]
    const int*   step  = (const int*)d_in[4];     // scalar

    float* out  = (float*)d_out;
    float* zq   = out;                 // 4194304
    float* emb  = out + 4194304;       // 4194304
    float* idxo = out + 8388608;       // 16384
    float* scal = out + 8404992;       // 4

    float* ws          = (float*)d_ws;
    float* cinv        = ws;           // 4096
    float* commit_part = ws + 4096;    // 16384
    float* commit_blk  = ws + 20480;   // 16

    hipLaunchKernelGGL(cinv_kernel, dim3(1024), dim3(256), 0, stream, cb, cinv);
    hipLaunchKernelGGL(row_kernel, dim3(N_ROWS), dim3(256), 0, stream,
                       u, z, cb, cinv, zq, emb, idxo, commit_part);
    hipLaunchKernelGGL(commit_reduce_kernel, dim3(16), dim3(256), 0, stream,
                       commit_part, commit_blk);
    hipLaunchKernelGGL(scalars_kernel, dim3(1), dim3(256), 0, stream,
                       commit_blk, usage, step, scal);
}